// Round 1
// baseline (995.855 us; speedup 1.0000x reference)
//
#include <hip/hip_runtime.h>
#include <hip/hip_bf16.h>

#define C_DIM 768
#define NHEADS 12
#define HDIM 64
#define BATCH 8
#define SEQ 1024
#define SCALE_F 0.125f          // 64^-0.5
#define TBL 3969                // 63*63 per head

// ---------------- ws layout (floats) ----------------
// q        [B][H][N][D]   off 0         (6291456)
// k        [B][H][N][D]   off 6291456
// v        [B][H][N][D]   off 12582912
// attn_out [B][N][C]      off 18874368  (6291456)
// btab     [H][63][63]    off 25165824  (47628)

// ============ GEMM core: C[M,N] = A[M,K] @ W[N,K]^T ============
// BM=BN=128, BK=16, 256 threads, 8x8 per thread.

__global__ __launch_bounds__(256)
void gemm_qkv_kernel(const float* __restrict__ A, const float* __restrict__ W,
                     float* __restrict__ qo, float* __restrict__ ko, float* __restrict__ vo,
                     int Kdim)
{
    __shared__ float As[16][132];
    __shared__ float Bs[16][132];
    const int m0 = blockIdx.y * 128;
    const int n0 = blockIdx.x * 128;
    const int t  = threadIdx.x;
    const int tx = t & 15, ty = t >> 4;
    float acc[8][8] = {};

    for (int k0 = 0; k0 < Kdim; k0 += 16) {
#pragma unroll
        for (int p = 0; p < 2; ++p) {
            int idx = t + p * 256;          // 0..511
            int row = idx >> 2;             // 0..127
            int cb  = (idx & 3) << 2;       // 0,4,8,12
            float4 av = *(const float4*)&A[(size_t)(m0 + row) * Kdim + k0 + cb];
            As[cb + 0][row] = av.x; As[cb + 1][row] = av.y;
            As[cb + 2][row] = av.z; As[cb + 3][row] = av.w;
            float4 bv = *(const float4*)&W[(size_t)(n0 + row) * Kdim + k0 + cb];
            Bs[cb + 0][row] = bv.x; Bs[cb + 1][row] = bv.y;
            Bs[cb + 2][row] = bv.z; Bs[cb + 3][row] = bv.w;
        }
        __syncthreads();
#pragma unroll
        for (int kk = 0; kk < 16; ++kk) {
            float4 a0 = *(const float4*)&As[kk][ty * 8];
            float4 a1 = *(const float4*)&As[kk][ty * 8 + 4];
            float4 b0 = *(const float4*)&Bs[kk][tx * 8];
            float4 b1 = *(const float4*)&Bs[kk][tx * 8 + 4];
            float ar[8] = {a0.x, a0.y, a0.z, a0.w, a1.x, a1.y, a1.z, a1.w};
            float br[8] = {b0.x, b0.y, b0.z, b0.w, b1.x, b1.y, b1.z, b1.w};
#pragma unroll
            for (int i = 0; i < 8; ++i)
#pragma unroll
                for (int j = 0; j < 8; ++j)
                    acc[i][j] = fmaf(ar[i], br[j], acc[i][j]);
        }
        __syncthreads();
    }

    // scatter epilogue into q/k/v [B][H][N][D]
#pragma unroll
    for (int i = 0; i < 8; ++i) {
        int mm = m0 + ty * 8 + i;
        int bb = mm >> 10, nn = mm & 1023;
#pragma unroll
        for (int j = 0; j < 8; ++j) {
            int o = n0 + tx * 8 + j;
            int which = o / 768;
            int rr = o - which * 768;
            int h = rr >> 6, d = rr & 63;
            float* dst = (which == 0) ? qo : (which == 1) ? ko : vo;
            dst[((((size_t)bb * NHEADS + h) * SEQ + nn) << 6) + d] = acc[i][j];
        }
    }
}

__global__ __launch_bounds__(256)
void gemm_proj_kernel(const float* __restrict__ A, const float* __restrict__ W,
                      const float* __restrict__ pb, float* __restrict__ out,
                      int Kdim)
{
    __shared__ float As[16][132];
    __shared__ float Bs[16][132];
    const int m0 = blockIdx.y * 128;
    const int n0 = blockIdx.x * 128;
    const int t  = threadIdx.x;
    const int tx = t & 15, ty = t >> 4;
    float acc[8][8] = {};

    for (int k0 = 0; k0 < Kdim; k0 += 16) {
#pragma unroll
        for (int p = 0; p < 2; ++p) {
            int idx = t + p * 256;
            int row = idx >> 2;
            int cb  = (idx & 3) << 2;
            float4 av = *(const float4*)&A[(size_t)(m0 + row) * Kdim + k0 + cb];
            As[cb + 0][row] = av.x; As[cb + 1][row] = av.y;
            As[cb + 2][row] = av.z; As[cb + 3][row] = av.w;
            float4 bv = *(const float4*)&W[(size_t)(n0 + row) * Kdim + k0 + cb];
            Bs[cb + 0][row] = bv.x; Bs[cb + 1][row] = bv.y;
            Bs[cb + 2][row] = bv.z; Bs[cb + 3][row] = bv.w;
        }
        __syncthreads();
#pragma unroll
        for (int kk = 0; kk < 16; ++kk) {
            float4 a0 = *(const float4*)&As[kk][ty * 8];
            float4 a1 = *(const float4*)&As[kk][ty * 8 + 4];
            float4 b0 = *(const float4*)&Bs[kk][tx * 8];
            float4 b1 = *(const float4*)&Bs[kk][tx * 8 + 4];
            float ar[8] = {a0.x, a0.y, a0.z, a0.w, a1.x, a1.y, a1.z, a1.w};
            float br[8] = {b0.x, b0.y, b0.z, b0.w, b1.x, b1.y, b1.z, b1.w};
#pragma unroll
            for (int i = 0; i < 8; ++i)
#pragma unroll
                for (int j = 0; j < 8; ++j)
                    acc[i][j] = fmaf(ar[i], br[j], acc[i][j]);
        }
        __syncthreads();
    }

#pragma unroll
    for (int i = 0; i < 8; ++i) {
        int mm = m0 + ty * 8 + i;
#pragma unroll
        for (int j = 0; j < 8; ++j) {
            int o = n0 + tx * 8 + j;
            out[(size_t)mm * C_DIM + o] = acc[i][j] + pb[o];
        }
    }
}

// ============ relative-position-bias table: btab[h][dy+31][dx+31] ============
__global__ __launch_bounds__(256)
void rpb_table_kernel(const float* __restrict__ w1, const float* __restrict__ b1,
                      const float* __restrict__ w2, const float* __restrict__ b2,
                      float* __restrict__ btab)
{
    int t = blockIdx.x * 256 + threadIdx.x;
    if (t >= TBL) return;
    float dy = (float)(t / 63 - 31);   // rel_y
    float dx = (float)(t % 63 - 31);   // rel_x
    float acc[NHEADS];
#pragma unroll
    for (int h = 0; h < NHEADS; ++h) acc[h] = b2[h];
    for (int j = 0; j < 64; ++j) {
        float hj = fmaf(w1[j * 2], dx, fmaf(w1[j * 2 + 1], dy, b1[j]));
        hj = fmaxf(hj, 0.f);
#pragma unroll
        for (int h = 0; h < NHEADS; ++h) acc[h] = fmaf(w2[h * 64 + j], hj, acc[h]);
    }
#pragma unroll
    for (int h = 0; h < NHEADS; ++h) btab[h * TBL + t] = acc[h];
}

// ============ fused flash attention: 64 q-rows x 64-key tiles ============
__global__ __launch_bounds__(256)
void attn_kernel(const float* __restrict__ q, const float* __restrict__ k,
                 const float* __restrict__ v, const float* __restrict__ btab,
                 float* __restrict__ out)
{
    __shared__ float Qst[64][68];   // [d][r]
    __shared__ float Kst[64][68];   // [d][c]
    __shared__ float Vs [64][68];   // [c][d]
    __shared__ float Pl [64][68];   // [c][r]

    const int qb = blockIdx.x, h = blockIdx.y, b = blockIdx.z;
    const int n0 = qb * 64;
    const int t  = threadIdx.x;
    const int tx = t & 15, ty = t >> 4;

    const size_t head_off = (((size_t)b * NHEADS + h) * SEQ) << 6;  // *64
    const float* qbase = q + head_off;
    const float* kbase = k + head_off;
    const float* vbase = v + head_off;
    const float* bt    = btab + h * TBL;

    // stage Q (transposed)
#pragma unroll
    for (int p = 0; p < 4; ++p) {
        int idx = t + p * 256;          // 0..1023
        int row = idx >> 4;             // 0..63
        int cb  = (idx & 15) << 2;      // 0..60 step 4
        float4 qv = *(const float4*)&qbase[((size_t)(n0 + row) << 6) + cb];
        Qst[cb + 0][row] = qv.x; Qst[cb + 1][row] = qv.y;
        Qst[cb + 2][row] = qv.z; Qst[cb + 3][row] = qv.w;
    }

    float m_i[4], l_i[4], o_acc[4][4];
#pragma unroll
    for (int i = 0; i < 4; ++i) {
        m_i[i] = -1e30f; l_i[i] = 0.f;
#pragma unroll
        for (int j = 0; j < 4; ++j) o_acc[i][j] = 0.f;
    }

    for (int kt = 0; kt < 16; ++kt) {
        const int c0 = kt * 64;
        __syncthreads();   // prev PV / Q-stage done before overwriting Kst/Vs
#pragma unroll
        for (int p = 0; p < 4; ++p) {
            int idx = t + p * 256;
            int row = idx >> 4;
            int cb  = (idx & 15) << 2;
            float4 kv = *(const float4*)&kbase[((size_t)(c0 + row) << 6) + cb];
            Kst[cb + 0][row] = kv.x; Kst[cb + 1][row] = kv.y;
            Kst[cb + 2][row] = kv.z; Kst[cb + 3][row] = kv.w;
            float4 vv = *(const float4*)&vbase[((size_t)(c0 + row) << 6) + cb];
            *(float4*)&Vs[row][cb] = vv;
        }
        __syncthreads();

        // S = Q K^T (this tile)
        float s[4][4] = {};
#pragma unroll 8
        for (int kk = 0; kk < 64; ++kk) {
            float4 a  = *(const float4*)&Qst[kk][ty * 4];
            float4 bq = *(const float4*)&Kst[kk][tx * 4];
            float ar[4] = {a.x, a.y, a.z, a.w};
            float br[4] = {bq.x, bq.y, bq.z, bq.w};
#pragma unroll
            for (int i = 0; i < 4; ++i)
#pragma unroll
                for (int j = 0; j < 4; ++j)
                    s[i][j] = fmaf(ar[i], br[j], s[i][j]);
        }

        // scale + relative position bias
#pragma unroll
        for (int i = 0; i < 4; ++i) {
            int nq = n0 + ty * 4 + i;
            int ny = nq >> 5, nx = nq & 31;
#pragma unroll
            for (int j = 0; j < 4; ++j) {
                int mk = c0 + tx * 4 + j;
                int dy = ny - (mk >> 5) + 31;
                int dx = nx - (mk & 31) + 31;
                s[i][j] = fmaf(s[i][j], SCALE_F, bt[dy * 63 + dx]);
            }
        }

        // online softmax (row r spread over 16 tx-lanes of one wave)
        float p_[4][4];
#pragma unroll
        for (int i = 0; i < 4; ++i) {
            float rm = fmaxf(fmaxf(s[i][0], s[i][1]), fmaxf(s[i][2], s[i][3]));
#pragma unroll
            for (int off = 1; off < 16; off <<= 1)
                rm = fmaxf(rm, __shfl_xor(rm, off));
            float mn = fmaxf(m_i[i], rm);
            float sc = __expf(m_i[i] - mn);
            float rs = 0.f;
#pragma unroll
            for (int j = 0; j < 4; ++j) {
                p_[i][j] = __expf(s[i][j] - mn);
                rs += p_[i][j];
            }
#pragma unroll
            for (int off = 1; off < 16; off <<= 1)
                rs += __shfl_xor(rs, off);
            l_i[i] = l_i[i] * sc + rs;
            m_i[i] = mn;
#pragma unroll
            for (int j = 0; j < 4; ++j) o_acc[i][j] *= sc;
        }

#pragma unroll
        for (int i = 0; i < 4; ++i)
#pragma unroll
            for (int j = 0; j < 4; ++j)
                Pl[tx * 4 + j][ty * 4 + i] = p_[i][j];
        __syncthreads();

        // O += P V
#pragma unroll 8
        for (int kk = 0; kk < 64; ++kk) {
            float4 a  = *(const float4*)&Pl[kk][ty * 4];
            float4 bv = *(const float4*)&Vs[kk][tx * 4];
            float ar[4] = {a.x, a.y, a.z, a.w};
            float br[4] = {bv.x, bv.y, bv.z, bv.w};
#pragma unroll
            for (int i = 0; i < 4; ++i)
#pragma unroll
                for (int j = 0; j < 4; ++j)
                    o_acc[i][j] = fmaf(ar[i], br[j], o_acc[i][j]);
        }
    }

    // normalize + write [B][N][C] with C-offset h*64
#pragma unroll
    for (int i = 0; i < 4; ++i) {
        int nq = n0 + ty * 4 + i;
        float inv = 1.f / l_i[i];
#pragma unroll
        for (int j = 0; j < 4; ++j)
            out[((size_t)b * SEQ + nq) * C_DIM + h * 64 + tx * 4 + j] = o_acc[i][j] * inv;
    }
}

extern "C" void kernel_launch(void* const* d_in, const int* in_sizes, int n_in,
                              void* d_out, int out_size, void* d_ws, size_t ws_size,
                              hipStream_t stream) {
    const float* x      = (const float*)d_in[0];
    const float* qkv_w  = (const float*)d_in[1];
    const float* proj_w = (const float*)d_in[2];
    const float* proj_b = (const float*)d_in[3];
    const float* rpb_w1 = (const float*)d_in[4];
    const float* rpb_b1 = (const float*)d_in[5];
    const float* rpb_w2 = (const float*)d_in[6];
    const float* rpb_b2 = (const float*)d_in[7];
    float* out = (float*)d_out;

    float* ws = (float*)d_ws;
    const size_t per = (size_t)BATCH * NHEADS * SEQ * HDIM;  // 6291456
    float* qbuf = ws;
    float* kbuf = ws + per;
    float* vbuf = ws + 2 * per;
    float* abuf = ws + 3 * per;          // attn out [B][N][C]
    float* btab = ws + 4 * per;          // 12*3969

    // bias table (independent of GEMM)
    rpb_table_kernel<<<dim3((TBL + 255) / 256), dim3(256), 0, stream>>>(
        rpb_w1, rpb_b1, rpb_w2, rpb_b2, btab);

    // QKV GEMM: [8192,768] @ [2304,768]^T
    gemm_qkv_kernel<<<dim3(2304 / 128, 8192 / 128), dim3(256), 0, stream>>>(
        x, qkv_w, qbuf, kbuf, vbuf, C_DIM);

    // fused attention
    attn_kernel<<<dim3(SEQ / 64, NHEADS, BATCH), dim3(256), 0, stream>>>(
        qbuf, kbuf, vbuf, btab, abuf);

    // proj GEMM: [8192,768] @ [768,768]^T + bias
    gemm_proj_kernel<<<dim3(768 / 128, 8192 / 128), dim3(256), 0, stream>>>(
        abuf, proj_w, proj_b, out, C_DIM);
}

// Round 3
// 627.817 us; speedup vs baseline: 1.5862x; 1.5862x over previous
//
#include <hip/hip_runtime.h>

#define C_DIM 768
#define NHEADS 12
#define HDIM 64
#define BATCH 8
#define SEQ 1024
#define SCALE_F 0.125f          // 64^-0.5
#define TBL 3969                // 63*63 per head

typedef float f32x4 __attribute__((ext_vector_type(4)));
typedef short s16x8 __attribute__((ext_vector_type(8)));

__device__ inline unsigned short f2bf(float f) {
    union { float f; unsigned u; } c; c.f = f;
    unsigned r = c.u + 0x7FFFu + ((c.u >> 16) & 1u);
    return (unsigned short)(r >> 16);
}

#define GLOAD_LDS16(gsrc, ldst)                                                   \
    __builtin_amdgcn_global_load_lds(                                             \
        (const __attribute__((address_space(1))) unsigned int*)(gsrc),            \
        (__attribute__((address_space(3))) unsigned int*)(ldst), 16, 0, 0)

// ---------------- ws layout (bytes) ----------------
// q_bf  [B][H][N][D] bf16   off 0          12582912
// k_bf  [B][H][N][D] bf16   off 12582912   12582912
// vT_bf [B][H][D][N] bf16   off 25165824   12582912
// abuf  [B][N][C]   f32     off 37748736   25165824
// btab  [H][63][63] f32     off 62914560   190512

// ============ QKV GEMM: f32 math, bf16 epilogue (q,k row-major; v transposed) ====
__global__ __launch_bounds__(256)
void gemm_qkv_kernel(const float* __restrict__ A, const float* __restrict__ W,
                     unsigned short* __restrict__ qo, unsigned short* __restrict__ ko,
                     unsigned short* __restrict__ vto, int Kdim)
{
    __shared__ float As[16][132];
    __shared__ float Bs[16][132];
    const int m0 = blockIdx.y * 128;
    const int n0 = blockIdx.x * 128;
    const int t  = threadIdx.x;
    const int tx = t & 15, ty = t >> 4;
    float acc[8][8] = {};

    for (int k0 = 0; k0 < Kdim; k0 += 16) {
#pragma unroll
        for (int p = 0; p < 2; ++p) {
            int idx = t + p * 256;
            int row = idx >> 2;
            int cb  = (idx & 3) << 2;
            float4 av = *(const float4*)&A[(size_t)(m0 + row) * Kdim + k0 + cb];
            As[cb + 0][row] = av.x; As[cb + 1][row] = av.y;
            As[cb + 2][row] = av.z; As[cb + 3][row] = av.w;
            float4 bv = *(const float4*)&W[(size_t)(n0 + row) * Kdim + k0 + cb];
            Bs[cb + 0][row] = bv.x; Bs[cb + 1][row] = bv.y;
            Bs[cb + 2][row] = bv.z; Bs[cb + 3][row] = bv.w;
        }
        __syncthreads();
#pragma unroll
        for (int kk = 0; kk < 16; ++kk) {
            float4 a0 = *(const float4*)&As[kk][ty * 8];
            float4 a1 = *(const float4*)&As[kk][ty * 8 + 4];
            float4 b0 = *(const float4*)&Bs[kk][tx * 8];
            float4 b1 = *(const float4*)&Bs[kk][tx * 8 + 4];
            float ar[8] = {a0.x, a0.y, a0.z, a0.w, a1.x, a1.y, a1.z, a1.w};
            float br[8] = {b0.x, b0.y, b0.z, b0.w, b1.x, b1.y, b1.z, b1.w};
#pragma unroll
            for (int i = 0; i < 8; ++i)
#pragma unroll
                for (int j = 0; j < 8; ++j)
                    acc[i][j] = fmaf(ar[i], br[j], acc[i][j]);
        }
        __syncthreads();
    }

    // epilogue: each 128-col block lies entirely inside q, k, or v (768%128==0)
    const int oc0   = n0 + tx * 8;          // 8 consecutive output cols
    const int which = oc0 / 768;            // 0=q 1=k 2=v
    const int rr0   = oc0 - which * 768;
    const int h     = rr0 >> 6;
    const int d0    = rr0 & 63;             // 8 consecutive d
#pragma unroll
    for (int i = 0; i < 8; ++i) {
        int mm = m0 + ty * 8 + i;
        int bb = mm >> 10, nn = mm & 1023;
        size_t headbase = ((size_t)(bb * NHEADS + h));
        if (which < 2) {
            s16x8 v8;
#pragma unroll
            for (int j = 0; j < 8; ++j) v8[j] = (short)f2bf(acc[i][j]);
            unsigned short* dst = (which == 0 ? qo : ko) +
                ((headbase * SEQ + nn) << 6) + d0;
            *(s16x8*)dst = v8;
        } else {
#pragma unroll
            for (int j = 0; j < 8; ++j)
                vto[((headbase << 6) + d0 + j) * SEQ + nn] = f2bf(acc[i][j]);
        }
    }
}

// ============ proj GEMM (unchanged f32) ============
__global__ __launch_bounds__(256)
void gemm_proj_kernel(const float* __restrict__ A, const float* __restrict__ W,
                      const float* __restrict__ pb, float* __restrict__ out,
                      int Kdim)
{
    __shared__ float As[16][132];
    __shared__ float Bs[16][132];
    const int m0 = blockIdx.y * 128;
    const int n0 = blockIdx.x * 128;
    const int t  = threadIdx.x;
    const int tx = t & 15, ty = t >> 4;
    float acc[8][8] = {};

    for (int k0 = 0; k0 < Kdim; k0 += 16) {
#pragma unroll
        for (int p = 0; p < 2; ++p) {
            int idx = t + p * 256;
            int row = idx >> 2;
            int cb  = (idx & 3) << 2;
            float4 av = *(const float4*)&A[(size_t)(m0 + row) * Kdim + k0 + cb];
            As[cb + 0][row] = av.x; As[cb + 1][row] = av.y;
            As[cb + 2][row] = av.z; As[cb + 3][row] = av.w;
            float4 bv = *(const float4*)&W[(size_t)(n0 + row) * Kdim + k0 + cb];
            Bs[cb + 0][row] = bv.x; Bs[cb + 1][row] = bv.y;
            Bs[cb + 2][row] = bv.z; Bs[cb + 3][row] = bv.w;
        }
        __syncthreads();
#pragma unroll
        for (int kk = 0; kk < 16; ++kk) {
            float4 a0 = *(const float4*)&As[kk][ty * 8];
            float4 a1 = *(const float4*)&As[kk][ty * 8 + 4];
            float4 b0 = *(const float4*)&Bs[kk][tx * 8];
            float4 b1 = *(const float4*)&Bs[kk][tx * 8 + 4];
            float ar[8] = {a0.x, a0.y, a0.z, a0.w, a1.x, a1.y, a1.z, a1.w};
            float br[8] = {b0.x, b0.y, b0.z, b0.w, b1.x, b1.y, b1.z, b1.w};
#pragma unroll
            for (int i = 0; i < 8; ++i)
#pragma unroll
                for (int j = 0; j < 8; ++j)
                    acc[i][j] = fmaf(ar[i], br[j], acc[i][j]);
        }
        __syncthreads();
    }

#pragma unroll
    for (int i = 0; i < 8; ++i) {
        int mm = m0 + ty * 8 + i;
#pragma unroll
        for (int j = 0; j < 8; ++j) {
            int o = n0 + tx * 8 + j;
            out[(size_t)mm * C_DIM + o] = acc[i][j] + pb[o];
        }
    }
}

// ============ relative-position-bias table ============
__global__ __launch_bounds__(256)
void rpb_table_kernel(const float* __restrict__ w1, const float* __restrict__ b1,
                      const float* __restrict__ w2, const float* __restrict__ b2,
                      float* __restrict__ btab)
{
    int t = blockIdx.x * 256 + threadIdx.x;
    if (t >= TBL) return;
    float dy = (float)(t / 63 - 31);
    float dx = (float)(t % 63 - 31);
    float acc[NHEADS];
#pragma unroll
    for (int h = 0; h < NHEADS; ++h) acc[h] = b2[h];
    for (int j = 0; j < 64; ++j) {
        float hj = fmaf(w1[j * 2], dx, fmaf(w1[j * 2 + 1], dy, b1[j]));
        hj = fmaxf(hj, 0.f);
#pragma unroll
        for (int h = 0; h < NHEADS; ++h) acc[h] = fmaf(w2[h * 64 + j], hj, acc[h]);
    }
#pragma unroll
    for (int h = 0; h < NHEADS; ++h) btab[h * TBL + t] = acc[h];
}

// ============ MFMA flash attention ============
// block = 4 waves; wave w owns q-rows [n0+16w, n0+16w+16); K/V tiles of 64.
// K_lds [key][d] and V_lds [d][key], both 128B rows, 16B-chunk XOR-swizzled by (row&7)
// via pre-swizzled global source (global_load_lds writes linearly).
// Bias: bidx computed for tile kt=0; key advances 64 = 2 grid rows per tile, so
// dy drops by 2 -> table index drops by 2*63 = 126 per tile (dx tile-invariant).
__global__ __launch_bounds__(256)
void attn_mfma_kernel(const unsigned short* __restrict__ qb,
                      const unsigned short* __restrict__ kb,
                      const unsigned short* __restrict__ vtb,
                      const float* __restrict__ btab,
                      float* __restrict__ out)
{
    __shared__ unsigned short Klds[64][64];    // 8 KB
    __shared__ unsigned short Vlds[64][64];    // 8 KB
    __shared__ unsigned short Plds[4][16][72]; // 9 KB, padded rows (144B) -> 2-way
    __shared__ float bt[TBL];                  // 15.5 KB

    const int qblk = blockIdx.x, h = blockIdx.y, b = blockIdx.z;
    const int n0 = qblk * 64;
    const int t = threadIdx.x;
    const int lane = t & 63, w = t >> 6;
    const int l15 = lane & 15, lhi = lane >> 4;

    for (int i = t; i < TBL; i += 256) bt[i] = btab[h * TBL + i];

    const size_t headND = ((size_t)(b * NHEADS + h)) * SEQ * HDIM;
    const char* qg = (const char*)(qb + headND);
    const char* kg = (const char*)(kb + headND);
    const char* vg = (const char*)(vtb + headND);   // [64][1024] bf16

    // Q A-fragments: row = l15 (within wave tile), k = lhi*8+j
    s16x8 qf0, qf1;
    {
        const char* qrow = qg + (size_t)(n0 + w * 16 + l15) * 128;
        qf0 = *(const s16x8*)(qrow + lhi * 16);
        qf1 = *(const s16x8*)(qrow + 64 + lhi * 16);
    }

    // bias index registers for kt=0: row r -> nq, col block n -> key l15+16n
    int bidx[4][4];
    {
        const int nq0 = n0 + w * 16 + lhi * 4;
#pragma unroll
        for (int r = 0; r < 4; ++r) {
            int nq = nq0 + r;
#pragma unroll
            for (int n = 0; n < 4; ++n) {
                int koff = l15 + 16 * n;
                int dy = (nq >> 5) - (koff >> 5) + 31;
                int dx = (nq & 31) - (koff & 31) + 31;
                bidx[r][n] = dy * 63 + dx;
            }
        }
    }

    f32x4 of[4];
    float m_i[4], l_i[4];
#pragma unroll
    for (int n = 0; n < 4; ++n) of[n] = (f32x4){0.f, 0.f, 0.f, 0.f};
#pragma unroll
    for (int r = 0; r < 4; ++r) { m_i[r] = -1e30f; l_i[r] = 0.f; }

    const int srow = (lane >> 3);        // staging row within 8-row group
    const int sch  = (lane & 7);         // staging chunk

    int boff = 0;                        // bias table offset: -126 per tile
    for (int kt = 0; kt < 16; ++kt) {
        const int c0 = kt * 64;
        __syncthreads();
        // stage K and V^T: wave w covers rows [16w,16w+16), 2 calls of 8 rows each
#pragma unroll
        for (int p = 0; p < 2; ++p) {
            int row = w * 16 + p * 8 + srow;
            int chk = sch ^ (row & 7);
            GLOAD_LDS16(kg + (size_t)(c0 + row) * 128 + chk * 16,
                        &Klds[w * 16 + p * 8][0]);
            GLOAD_LDS16(vg + (size_t)row * 2048 + c0 * 2 + chk * 16,
                        &Vlds[w * 16 + p * 8][0]);
        }
        asm volatile("s_waitcnt vmcnt(0)" ::: "memory");
        __syncthreads();

        // ---- S = Q K^T : D[row][key], key block n ----
        f32x4 sf[4];
#pragma unroll
        for (int n = 0; n < 4; ++n) {
            int key = 16 * n + l15;
            const char* krow = (const char*)&Klds[key][0];
            s16x8 kf0 = *(const s16x8*)(krow + ((lhi     ^ (key & 7)) * 16));
            s16x8 kf1 = *(const s16x8*)(krow + (((4+lhi) ^ (key & 7)) * 16));
            f32x4 z = (f32x4){0.f, 0.f, 0.f, 0.f};
            sf[n] = __builtin_amdgcn_mfma_f32_16x16x32_bf16(qf0, kf0, z, 0, 0, 0);
            sf[n] = __builtin_amdgcn_mfma_f32_16x16x32_bf16(qf1, kf1, sf[n], 0, 0, 0);
        }

        // ---- bias + online softmax (rows spread over 16-lane groups) ----
#pragma unroll
        for (int r = 0; r < 4; ++r) {
            float s0 = fmaf(sf[0][r], SCALE_F, bt[bidx[r][0] + boff]);
            float s1 = fmaf(sf[1][r], SCALE_F, bt[bidx[r][1] + boff]);
            float s2 = fmaf(sf[2][r], SCALE_F, bt[bidx[r][2] + boff]);
            float s3 = fmaf(sf[3][r], SCALE_F, bt[bidx[r][3] + boff]);
            float mx = fmaxf(fmaxf(s0, s1), fmaxf(s2, s3));
#pragma unroll
            for (int off = 1; off < 16; off <<= 1)
                mx = fmaxf(mx, __shfl_xor(mx, off));
            float mn = fmaxf(m_i[r], mx);
            float sc = __expf(m_i[r] - mn);
            float p0 = __expf(s0 - mn);
            float p1 = __expf(s1 - mn);
            float p2 = __expf(s2 - mn);
            float p3 = __expf(s3 - mn);
            float rs = (p0 + p1) + (p2 + p3);
#pragma unroll
            for (int off = 1; off < 16; off <<= 1)
                rs += __shfl_xor(rs, off);
            l_i[r] = l_i[r] * sc + rs;
            m_i[r] = mn;
            of[0][r] *= sc; of[1][r] *= sc; of[2][r] *= sc; of[3][r] *= sc;
            int prow = lhi * 4 + r;
            Plds[w][prow][l15 +  0] = f2bf(p0);
            Plds[w][prow][l15 + 16] = f2bf(p1);
            Plds[w][prow][l15 + 32] = f2bf(p2);
            Plds[w][prow][l15 + 48] = f2bf(p3);
        }
        boff -= 126;
        asm volatile("s_waitcnt lgkmcnt(0)" ::: "memory");
        __builtin_amdgcn_sched_barrier(0);

        // ---- O += P V : A = P[row][key], B = V^T-read (col=d, k=key) ----
#pragma unroll
        for (int kwin = 0; kwin < 2; ++kwin) {
            s16x8 pa = *(const s16x8*)&Plds[w][l15][kwin * 32 + lhi * 8];
#pragma unroll
            for (int n = 0; n < 4; ++n) {
                int d  = 16 * n + l15;
                int cd = kwin * 4 + lhi;
                const char* vrow = (const char*)&Vlds[d][0];
                s16x8 vf = *(const s16x8*)(vrow + ((cd ^ (d & 7)) * 16));
                of[n] = __builtin_amdgcn_mfma_f32_16x16x32_bf16(pa, vf, of[n], 0, 0, 0);
            }
        }
    }

    // ---- epilogue: out[b][nq][h*64 + d] = O/l ----
#pragma unroll
    for (int r = 0; r < 4; ++r) {
        float inv = 1.f / l_i[r];
        int nq = n0 + w * 16 + lhi * 4 + r;
        float* orow = out + ((size_t)b * SEQ + nq) * C_DIM + h * 64;
#pragma unroll
        for (int n = 0; n < 4; ++n)
            orow[16 * n + l15] = of[n][r] * inv;
    }
}

extern "C" void kernel_launch(void* const* d_in, const int* in_sizes, int n_in,
                              void* d_out, int out_size, void* d_ws, size_t ws_size,
                              hipStream_t stream) {
    const float* x      = (const float*)d_in[0];
    const float* qkv_w  = (const float*)d_in[1];
    const float* proj_w = (const float*)d_in[2];
    const float* proj_b = (const float*)d_in[3];
    const float* rpb_w1 = (const float*)d_in[4];
    const float* rpb_b1 = (const float*)d_in[5];
    const float* rpb_w2 = (const float*)d_in[6];
    const float* rpb_b2 = (const float*)d_in[7];
    float* out = (float*)d_out;

    char* wsb = (char*)d_ws;
    unsigned short* qbuf = (unsigned short*)(wsb);
    unsigned short* kbuf = (unsigned short*)(wsb + 12582912);
    unsigned short* vtbuf = (unsigned short*)(wsb + 25165824);
    float* abuf = (float*)(wsb + 37748736);
    float* btab = (float*)(wsb + 62914560);

    rpb_table_kernel<<<dim3((TBL + 255) / 256), dim3(256), 0, stream>>>(
        rpb_w1, rpb_b1, rpb_w2, rpb_b2, btab);

    gemm_qkv_kernel<<<dim3(2304 / 128, 8192 / 128), dim3(256), 0, stream>>>(
        x, qkv_w, qbuf, kbuf, vtbuf, C_DIM);

    attn_mfma_kernel<<<dim3(SEQ / 64, NHEADS, BATCH), dim3(256), 0, stream>>>(
        qbuf, kbuf, vtbuf, btab, abuf);

    gemm_proj_kernel<<<dim3(768 / 128, 8192 / 128), dim3(256), 0, stream>>>(
        abuf, proj_w, proj_b, out, C_DIM);
}

// Round 4
// 261.840 us; speedup vs baseline: 3.8033x; 2.3977x over previous
//
#include <hip/hip_runtime.h>

#define C_DIM 768
#define NHEADS 12
#define HDIM 64
#define BATCH 8
#define SEQ 1024
#define SCALE_F 0.125f          // 64^-0.5
#define TBL 3969                // 63*63 per head

typedef float f32x4 __attribute__((ext_vector_type(4)));
typedef short s16x4 __attribute__((ext_vector_type(4)));
typedef short s16x8 __attribute__((ext_vector_type(8)));

__device__ inline unsigned short f2bf(float f) {
    union { float f; unsigned u; } c; c.f = f;
    unsigned r = c.u + 0x7FFFu + ((c.u >> 16) & 1u);
    return (unsigned short)(r >> 16);
}

#define GLOAD_LDS16(gsrc, ldst)                                                   \
    __builtin_amdgcn_global_load_lds(                                             \
        (const __attribute__((address_space(1))) unsigned int*)(gsrc),            \
        (__attribute__((address_space(3))) unsigned int*)(ldst), 16, 0, 0)

// ---------------- ws layout (bytes) ----------------
// q_bf    [B][H][N][D] bf16   off 0          12582912
// k_bf    [B][H][N][D] bf16   off 12582912   12582912
// vT_bf   [B][H][D][N] bf16   off 25165824   12582912
// abuf    [B][N][C]    bf16   off 37748736   12582912
// btab    [H][63][63]  f32    off 50331648   190512
// x_bf    [8192][768]  bf16   off 50522160   12582912
// qkvw_bf [2304][768]  bf16   off 63105072   3538944
// projw_bf[768][768]   bf16   off 66644016   1179648

// ============ f32 -> bf16 cast, 8 elems/thread ============
__global__ __launch_bounds__(256)
void cvt_bf16_kernel(const float* __restrict__ in, unsigned short* __restrict__ out,
                     int n8)
{
    int i = blockIdx.x * 256 + threadIdx.x;
    if (i >= n8) return;
    const float4* p = (const float4*)in + (size_t)i * 2;
    float4 a = p[0], b = p[1];
    s16x8 v;
    v[0] = (short)f2bf(a.x); v[1] = (short)f2bf(a.y);
    v[2] = (short)f2bf(a.z); v[3] = (short)f2bf(a.w);
    v[4] = (short)f2bf(b.x); v[5] = (short)f2bf(b.y);
    v[6] = (short)f2bf(b.z); v[7] = (short)f2bf(b.w);
    *((s16x8*)out + i) = v;
}

// ============ MFMA GEMM: C[M,N] = A[M,K] @ W[N,K]^T, bf16 in ============
// 128x128x32 tiles, 4 waves 2x2, global_load_lds w/ pre-swizzled source
// (chunk ^= row&3), swapped-operand MFMA for contiguous epilogue stores.

__global__ __launch_bounds__(256)
void gemm_qkv_mfma(const unsigned short* __restrict__ A,
                   const unsigned short* __restrict__ W,
                   unsigned short* __restrict__ qo, unsigned short* __restrict__ ko,
                   unsigned short* __restrict__ vto)
{
    __shared__ unsigned short Al[128][32];   // 8 KB
    __shared__ unsigned short Bl[128][32];   // 8 KB
    const int m0 = blockIdx.y * 128;
    const int n0 = blockIdx.x * 128;
    const int t = threadIdx.x;
    const int lane = t & 63, w = t >> 6;
    const int wr = w >> 1, wc = w & 1;
    const int l15 = lane & 15, lhi = lane >> 4;

    const int which = n0 / 768;              // 0=q 1=k 2=v (block-uniform)
    const int ncol0 = n0 - which * 768;

    const int srow   = lane >> 2;            // 0..15 within 16-row group
    const int schunk = (lane & 3) ^ (srow & 3);

    f32x4 acc[4][4];
#pragma unroll
    for (int i = 0; i < 4; ++i)
#pragma unroll
        for (int j = 0; j < 4; ++j)
            acc[i][j] = (f32x4){0.f, 0.f, 0.f, 0.f};

    const char* Ab = (const char*)A;
    const char* Wb = (const char*)W;
    const int rdch = (lhi ^ (l15 & 3)) * 16; // swizzled read chunk byte offset

    for (int k0 = 0; k0 < 768; k0 += 32) {
        __syncthreads();
#pragma unroll
        for (int p = 0; p < 2; ++p) {
            int rbase = (2 * w + p) * 16;
            GLOAD_LDS16(Ab + ((size_t)(m0 + rbase + srow) * 768 + k0) * 2 + schunk * 16,
                        &Al[rbase][0]);
            GLOAD_LDS16(Wb + ((size_t)(n0 + rbase + srow) * 768 + k0) * 2 + schunk * 16,
                        &Bl[rbase][0]);
        }
        asm volatile("s_waitcnt vmcnt(0)" ::: "memory");
        __syncthreads();

        s16x8 ar[4], br[4];
#pragma unroll
        for (int i = 0; i < 4; ++i) {
            ar[i] = *(const s16x8*)((const char*)&Al[wr * 64 + i * 16 + l15][0] + rdch);
            br[i] = *(const s16x8*)((const char*)&Bl[wc * 64 + i * 16 + l15][0] + rdch);
        }
        if (which < 2) {   // swapped: acc = C^T frag (col=l15 is m-row)
#pragma unroll
            for (int i = 0; i < 4; ++i)
#pragma unroll
                for (int j = 0; j < 4; ++j)
                    acc[i][j] = __builtin_amdgcn_mfma_f32_16x16x32_bf16(
                        br[j], ar[i], acc[i][j], 0, 0, 0);
        } else {           // normal: row=lhi*4+reg is m-row
#pragma unroll
            for (int i = 0; i < 4; ++i)
#pragma unroll
                for (int j = 0; j < 4; ++j)
                    acc[i][j] = __builtin_amdgcn_mfma_f32_16x16x32_bf16(
                        ar[i], br[j], acc[i][j], 0, 0, 0);
        }
    }

    const int h = (ncol0 >> 6) + wc;         // 64-col wave block = one head's d-range
    if (which < 2) {
        unsigned short* dst0 = (which == 0) ? qo : ko;
#pragma unroll
        for (int i = 0; i < 4; ++i) {
            int mm = m0 + wr * 64 + i * 16 + l15;
            int b_ = mm >> 10, nn = mm & 1023;
            unsigned short* rowp = dst0 + (((size_t)(b_ * NHEADS + h) * SEQ + nn) << 6);
#pragma unroll
            for (int j = 0; j < 4; ++j) {
                s16x4 v;
#pragma unroll
                for (int r = 0; r < 4; ++r) v[r] = (short)f2bf(acc[i][j][r]);
                *(s16x4*)(rowp + j * 16 + lhi * 4) = v;   // d contiguous over reg
            }
        }
    } else {
#pragma unroll
        for (int i = 0; i < 4; ++i) {
            int mm0 = m0 + wr * 64 + i * 16 + lhi * 4;
            int b_ = mm0 >> 10, nn0 = mm0 & 1023;
#pragma unroll
            for (int j = 0; j < 4; ++j) {
                int d = j * 16 + l15;
                s16x4 v;
#pragma unroll
                for (int r = 0; r < 4; ++r) v[r] = (short)f2bf(acc[i][j][r]);
                *(s16x4*)(vto + (((size_t)(b_ * NHEADS + h) * HDIM + d) << 10) + nn0) = v;
            }
        }
    }
}

__global__ __launch_bounds__(256)
void gemm_proj_mfma(const unsigned short* __restrict__ A,
                    const unsigned short* __restrict__ W,
                    const float* __restrict__ pb, float* __restrict__ out)
{
    __shared__ unsigned short Al[128][32];
    __shared__ unsigned short Bl[128][32];
    const int m0 = blockIdx.y * 128;
    const int n0 = blockIdx.x * 128;
    const int t = threadIdx.x;
    const int lane = t & 63, w = t >> 6;
    const int wr = w >> 1, wc = w & 1;
    const int l15 = lane & 15, lhi = lane >> 4;

    const int srow   = lane >> 2;
    const int schunk = (lane & 3) ^ (srow & 3);

    f32x4 acc[4][4];
#pragma unroll
    for (int i = 0; i < 4; ++i)
#pragma unroll
        for (int j = 0; j < 4; ++j)
            acc[i][j] = (f32x4){0.f, 0.f, 0.f, 0.f};

    const char* Ab = (const char*)A;
    const char* Wb = (const char*)W;
    const int rdch = (lhi ^ (l15 & 3)) * 16;

    for (int k0 = 0; k0 < 768; k0 += 32) {
        __syncthreads();
#pragma unroll
        for (int p = 0; p < 2; ++p) {
            int rbase = (2 * w + p) * 16;
            GLOAD_LDS16(Ab + ((size_t)(m0 + rbase + srow) * 768 + k0) * 2 + schunk * 16,
                        &Al[rbase][0]);
            GLOAD_LDS16(Wb + ((size_t)(n0 + rbase + srow) * 768 + k0) * 2 + schunk * 16,
                        &Bl[rbase][0]);
        }
        asm volatile("s_waitcnt vmcnt(0)" ::: "memory");
        __syncthreads();

        s16x8 ar[4], br[4];
#pragma unroll
        for (int i = 0; i < 4; ++i) {
            ar[i] = *(const s16x8*)((const char*)&Al[wr * 64 + i * 16 + l15][0] + rdch);
            br[i] = *(const s16x8*)((const char*)&Bl[wc * 64 + i * 16 + l15][0] + rdch);
        }
#pragma unroll
        for (int i = 0; i < 4; ++i)
#pragma unroll
            for (int j = 0; j < 4; ++j)
                acc[i][j] = __builtin_amdgcn_mfma_f32_16x16x32_bf16(
                    br[j], ar[i], acc[i][j], 0, 0, 0);   // swapped -> float4 stores
    }

    float4 bias[4];
#pragma unroll
    for (int j = 0; j < 4; ++j)
        bias[j] = *(const float4*)&pb[n0 + wc * 64 + j * 16 + lhi * 4];
#pragma unroll
    for (int i = 0; i < 4; ++i) {
        int mm = m0 + wr * 64 + i * 16 + l15;
        float* rowp = out + (size_t)mm * C_DIM + n0 + wc * 64;
#pragma unroll
        for (int j = 0; j < 4; ++j) {
            float4 o = {acc[i][j][0] + bias[j].x, acc[i][j][1] + bias[j].y,
                        acc[i][j][2] + bias[j].z, acc[i][j][3] + bias[j].w};
            *(float4*)(rowp + j * 16 + lhi * 4) = o;
        }
    }
}

// ============ relative-position-bias table ============
__global__ __launch_bounds__(256)
void rpb_table_kernel(const float* __restrict__ w1, const float* __restrict__ b1,
                      const float* __restrict__ w2, const float* __restrict__ b2,
                      float* __restrict__ btab)
{
    int t = blockIdx.x * 256 + threadIdx.x;
    if (t >= TBL) return;
    float dy = (float)(t / 63 - 31);
    float dx = (float)(t % 63 - 31);
    float acc[NHEADS];
#pragma unroll
    for (int h = 0; h < NHEADS; ++h) acc[h] = b2[h];
    for (int j = 0; j < 64; ++j) {
        float hj = fmaf(w1[j * 2], dx, fmaf(w1[j * 2 + 1], dy, b1[j]));
        hj = fmaxf(hj, 0.f);
#pragma unroll
        for (int h = 0; h < NHEADS; ++h) acc[h] = fmaf(w2[h * 64 + j], hj, acc[h]);
    }
#pragma unroll
    for (int h = 0; h < NHEADS; ++h) btab[h * TBL + t] = acc[h];
}

// ============ MFMA flash attention (bf16 output) ============
__global__ __launch_bounds__(256)
void attn_mfma_kernel(const unsigned short* __restrict__ qb,
                      const unsigned short* __restrict__ kb,
                      const unsigned short* __restrict__ vtb,
                      const float* __restrict__ btab,
                      unsigned short* __restrict__ out)
{
    __shared__ unsigned short Klds[64][64];    // 8 KB
    __shared__ unsigned short Vlds[64][64];    // 8 KB
    __shared__ unsigned short Plds[4][16][72]; // 9 KB
    __shared__ float bt[TBL];                  // 15.5 KB

    const int qblk = blockIdx.x, h = blockIdx.y, b = blockIdx.z;
    const int n0 = qblk * 64;
    const int t = threadIdx.x;
    const int lane = t & 63, w = t >> 6;
    const int l15 = lane & 15, lhi = lane >> 4;

    for (int i = t; i < TBL; i += 256) bt[i] = btab[h * TBL + i];

    const size_t headND = ((size_t)(b * NHEADS + h)) * SEQ * HDIM;
    const char* qg = (const char*)(qb + headND);
    const char* kg = (const char*)(kb + headND);
    const char* vg = (const char*)(vtb + headND);   // [64][1024] bf16

    s16x8 qf0, qf1;
    {
        const char* qrow = qg + (size_t)(n0 + w * 16 + l15) * 128;
        qf0 = *(const s16x8*)(qrow + lhi * 16);
        qf1 = *(const s16x8*)(qrow + 64 + lhi * 16);
    }

    int bidx[4][4];
    {
        const int nq0 = n0 + w * 16 + lhi * 4;
#pragma unroll
        for (int r = 0; r < 4; ++r) {
            int nq = nq0 + r;
#pragma unroll
            for (int n = 0; n < 4; ++n) {
                int koff = l15 + 16 * n;
                int dy = (nq >> 5) - (koff >> 5) + 31;
                int dx = (nq & 31) - (koff & 31) + 31;
                bidx[r][n] = dy * 63 + dx;
            }
        }
    }

    f32x4 of[4];
    float m_i[4], l_i[4];
#pragma unroll
    for (int n = 0; n < 4; ++n) of[n] = (f32x4){0.f, 0.f, 0.f, 0.f};
#pragma unroll
    for (int r = 0; r < 4; ++r) { m_i[r] = -1e30f; l_i[r] = 0.f; }

    const int srow = (lane >> 3);
    const int sch  = (lane & 7);

    int boff = 0;                        // bias table offset: -126 per tile
    for (int kt = 0; kt < 16; ++kt) {
        const int c0 = kt * 64;
        __syncthreads();
#pragma unroll
        for (int p = 0; p < 2; ++p) {
            int row = w * 16 + p * 8 + srow;
            int chk = sch ^ (row & 7);
            GLOAD_LDS16(kg + (size_t)(c0 + row) * 128 + chk * 16,
                        &Klds[w * 16 + p * 8][0]);
            GLOAD_LDS16(vg + (size_t)row * 2048 + c0 * 2 + chk * 16,
                        &Vlds[w * 16 + p * 8][0]);
        }
        asm volatile("s_waitcnt vmcnt(0)" ::: "memory");
        __syncthreads();

        f32x4 sf[4];
#pragma unroll
        for (int n = 0; n < 4; ++n) {
            int key = 16 * n + l15;
            const char* krow = (const char*)&Klds[key][0];
            s16x8 kf0 = *(const s16x8*)(krow + ((lhi     ^ (key & 7)) * 16));
            s16x8 kf1 = *(const s16x8*)(krow + (((4+lhi) ^ (key & 7)) * 16));
            f32x4 z = (f32x4){0.f, 0.f, 0.f, 0.f};
            sf[n] = __builtin_amdgcn_mfma_f32_16x16x32_bf16(qf0, kf0, z, 0, 0, 0);
            sf[n] = __builtin_amdgcn_mfma_f32_16x16x32_bf16(qf1, kf1, sf[n], 0, 0, 0);
        }

#pragma unroll
        for (int r = 0; r < 4; ++r) {
            float s0 = fmaf(sf[0][r], SCALE_F, bt[bidx[r][0] + boff]);
            float s1 = fmaf(sf[1][r], SCALE_F, bt[bidx[r][1] + boff]);
            float s2 = fmaf(sf[2][r], SCALE_F, bt[bidx[r][2] + boff]);
            float s3 = fmaf(sf[3][r], SCALE_F, bt[bidx[r][3] + boff]);
            float mx = fmaxf(fmaxf(s0, s1), fmaxf(s2, s3));
#pragma unroll
            for (int off = 1; off < 16; off <<= 1)
                mx = fmaxf(mx, __shfl_xor(mx, off));
            float mn = fmaxf(m_i[r], mx);
            float sc = __expf(m_i[r] - mn);
            float p0 = __expf(s0 - mn);
            float p1 = __expf(s1 - mn);
            float p2 = __expf(s2 - mn);
            float p3 = __expf(s3 - mn);
            float rs = (p0 + p1) + (p2 + p3);
#pragma unroll
            for (int off = 1; off < 16; off <<= 1)
                rs += __shfl_xor(rs, off);
            l_i[r] = l_i[r] * sc + rs;
            m_i[r] = mn;
            of[0][r] *= sc; of[1][r] *= sc; of[2][r] *= sc; of[3][r] *= sc;
            int prow = lhi * 4 + r;
            Plds[w][prow][l15 +  0] = f2bf(p0);
            Plds[w][prow][l15 + 16] = f2bf(p1);
            Plds[w][prow][l15 + 32] = f2bf(p2);
            Plds[w][prow][l15 + 48] = f2bf(p3);
        }
        boff -= 126;
        asm volatile("s_waitcnt lgkmcnt(0)" ::: "memory");
        __builtin_amdgcn_sched_barrier(0);

#pragma unroll
        for (int kwin = 0; kwin < 2; ++kwin) {
            s16x8 pa = *(const s16x8*)&Plds[w][l15][kwin * 32 + lhi * 8];
#pragma unroll
            for (int n = 0; n < 4; ++n) {
                int d  = 16 * n + l15;
                int cd = kwin * 4 + lhi;
                const char* vrow = (const char*)&Vlds[d][0];
                s16x8 vf = *(const s16x8*)(vrow + ((cd ^ (d & 7)) * 16));
                of[n] = __builtin_amdgcn_mfma_f32_16x16x32_bf16(pa, vf, of[n], 0, 0, 0);
            }
        }
    }

#pragma unroll
    for (int r = 0; r < 4; ++r) {
        float inv = 1.f / l_i[r];
        int nq = n0 + w * 16 + lhi * 4 + r;
        unsigned short* orow = out + ((size_t)b * SEQ + nq) * C_DIM + h * 64;
#pragma unroll
        for (int n = 0; n < 4; ++n)
            orow[16 * n + l15] = f2bf(of[n][r] * inv);
    }
}

extern "C" void kernel_launch(void* const* d_in, const int* in_sizes, int n_in,
                              void* d_out, int out_size, void* d_ws, size_t ws_size,
                              hipStream_t stream) {
    const float* x      = (const float*)d_in[0];
    const float* qkv_w  = (const float*)d_in[1];
    const float* proj_w = (const float*)d_in[2];
    const float* proj_b = (const float*)d_in[3];
    const float* rpb_w1 = (const float*)d_in[4];
    const float* rpb_b1 = (const float*)d_in[5];
    const float* rpb_w2 = (const float*)d_in[6];
    const float* rpb_b2 = (const float*)d_in[7];
    float* out = (float*)d_out;

    char* wsb = (char*)d_ws;
    unsigned short* qbuf    = (unsigned short*)(wsb);
    unsigned short* kbuf    = (unsigned short*)(wsb + 12582912);
    unsigned short* vtbuf   = (unsigned short*)(wsb + 25165824);
    unsigned short* abuf    = (unsigned short*)(wsb + 37748736);
    float*          btab    = (float*)         (wsb + 50331648);
    unsigned short* xbf     = (unsigned short*)(wsb + 50522160);
    unsigned short* qkvwbf  = (unsigned short*)(wsb + 63105072);
    unsigned short* projwbf = (unsigned short*)(wsb + 66644016);

    // f32 -> bf16 casts
    cvt_bf16_kernel<<<dim3(786432 / 256), dim3(256), 0, stream>>>(x, xbf, 786432);
    cvt_bf16_kernel<<<dim3(864), dim3(256), 0, stream>>>(qkv_w, qkvwbf, 221184);
    cvt_bf16_kernel<<<dim3(288), dim3(256), 0, stream>>>(proj_w, projwbf, 73728);

    rpb_table_kernel<<<dim3((TBL + 255) / 256), dim3(256), 0, stream>>>(
        rpb_w1, rpb_b1, rpb_w2, rpb_b2, btab);

    // QKV GEMM: [8192,768] @ [2304,768]^T (MFMA)
    gemm_qkv_mfma<<<dim3(18, 64), dim3(256), 0, stream>>>(
        xbf, qkvwbf, qbuf, kbuf, vtbuf);

    attn_mfma_kernel<<<dim3(SEQ / 64, NHEADS, BATCH), dim3(256), 0, stream>>>(
        qbuf, kbuf, vtbuf, btab, abuf);

    // proj GEMM: [8192,768] @ [768,768]^T + bias (MFMA)
    gemm_proj_mfma<<<dim3(6, 64), dim3(256), 0, stream>>>(
        abuf, projwbf, proj_b, out);
}